// Round 1
// baseline (612.716 us; speedup 1.0000x reference)
//
#include <hip/hip_runtime.h>
#include <hip/hip_bf16.h>

// FastCMIF: sliding-window mutual information, computed with exact integer
// joint histograms instead of the reference's 256 FFT convolutions.
//
// Per output pixel (y,x): joint counts c_kl = #{(r,c) in 48x48 :
//   imgbin(y+r-24, x+c-24) == k && tbin(r,c) == l }, image positions outside
//   the frame excluded (sentinel bin 16 -> ignored histogram row).
// MI = (1/N) [ sum c_kl ln c_kl - sum c_k ln c_k - sum c_l ln c_l + N ln N ].
//
// Workspace layout:
//   [0, 373248)           : padded binned images, u8, 2 x 432 x 432 (sentinel 16)
//   [373248, 375552)      : packed template bins, 2 x 288 u32 (8 x 4-bit per word)
//   [375552, 375584)      : min/max: im0(mn,mx) im1 t0 t1  (8 floats)

#define IMH 384
#define IMW 384
#define TH 48
#define TW 48
#define PAD 24          // window rows y-24 .. y+23 ; padded idx = y + r
#define PH 432          // 384 + 48
#define PIMG (PH*PH)    // 186624
#define HSTRIDE 137     // per-thread histogram stride in words (17*8 + 1 pad)

__global__ void k_minmax(const float* __restrict__ im, const float* __restrict__ tm,
                         float* __restrict__ mnmx) {
    int blk = blockIdx.x;
    const float* src;
    int n;
    if (blk < 2) { src = im + blk * (IMH*IMW); n = IMH*IMW; }
    else         { src = tm + (blk-2) * (TH*TW); n = TH*TW; }
    float mn = 3.402823466e+38f, mx = -3.402823466e+38f;
    for (int i = threadIdx.x; i < n; i += 256) {
        float v = src[i];
        mn = fminf(mn, v);
        mx = fmaxf(mx, v);
    }
    for (int o = 32; o > 0; o >>= 1) {
        mn = fminf(mn, __shfl_down(mn, o));
        mx = fmaxf(mx, __shfl_down(mx, o));
    }
    __shared__ float smn[4], smx[4];
    int w = threadIdx.x >> 6;
    if ((threadIdx.x & 63) == 0) { smn[w] = mn; smx[w] = mx; }
    __syncthreads();
    if (threadIdx.x == 0) {
        mn = fminf(fminf(smn[0], smn[1]), fminf(smn[2], smn[3]));
        mx = fmaxf(fmaxf(smx[0], smx[1]), fmaxf(smx[2], smx[3]));
        mnmx[blk*2]   = mn;
        mnmx[blk*2+1] = mx;
    }
}

// bin + pad images. One thread per padded position (2*432*432 = 373248).
__global__ void k_binpad(const float* __restrict__ im, const float* __restrict__ mnmx,
                         unsigned char* __restrict__ pIm) {
    int idx = blockIdx.x * 256 + threadIdx.x;
    int b = idx / PIMG;
    int rem = idx - b * PIMG;
    int py = rem / PH, px = rem - py * PH;
    unsigned char bin = 16;   // sentinel = outside image
    if (py >= PAD && py < PAD + IMH && px >= PAD && px < PAD + IMW) {
        float v = im[b * (IMH*IMW) + (py - PAD) * IMW + (px - PAD)];
        float mn = mnmx[2*b], mx = mnmx[2*b+1];
        // replicate reference numerics exactly: sub, IEEE div, mul 15, floor
        float r = (v - mn) / (mx - mn);
        bin = (unsigned char)(int)floorf(r * 15.0f);
    }
    pIm[idx] = bin;
}

// bin + pack template: 8 x 4-bit bins per u32, 288 words per template.
__global__ void k_tpack(const float* __restrict__ tm, const float* __restrict__ mnmx,
                        unsigned* __restrict__ pT) {
    int b = blockIdx.x;
    float mn = mnmx[4 + 2*b], mx = mnmx[5 + 2*b];
    const float* t = tm + b * (TH*TW);
    for (int w = threadIdx.x; w < 288; w += 64) {
        unsigned word = 0;
        for (int j = 0; j < 8; ++j) {
            float v = t[w*8 + j];
            float r = (v - mn) / (mx - mn);
            int bin = (int)floorf(r * 15.0f);
            word |= ((unsigned)bin) << (4*j);
        }
        pT[b*288 + w] = word;
    }
}

// main: 64 threads = 8x8 output tile per block. Per-thread 17x16 joint
// histogram in LDS, two u16 counters packed per u32, updated via ds_add_u32.
__global__ void k_main(const unsigned char* __restrict__ pIm,
                       const unsigned* __restrict__ pT,
                       float* __restrict__ out) {
    __shared__ unsigned hist[64 * HSTRIDE];   // 35072 B
    __shared__ unsigned tile[55 * 14];        // 55 rows x 56 bytes of image bins
    __shared__ unsigned twl[288];             // packed template bins
    const int tid = threadIdx.x;
    const int tx = tid & 7, ty = tid >> 3;
    const int b = blockIdx.z;
    const int X0 = blockIdx.x << 3, Y0 = blockIdx.y << 3;
    const unsigned char* img = pIm + b * PIMG;

    for (int i = tid; i < 288; i += 64) twl[i] = pT[b*288 + i];
    for (int i = tid; i < 55*14; i += 64) {
        int r = i / 14, w = i - r*14;
        const unsigned* gp = (const unsigned*)(img + (Y0 + r) * PH + X0); // aligned: PH%4==0, X0%8==0
        tile[r*14 + w] = gp[w];
    }
    const int histBase = tid * HSTRIDE;
    for (int i = 0; i < HSTRIDE; ++i) hist[histBase + i] = 0;
    __syncthreads();

    const int sh = (tx & 3) * 8;
    for (int r = 0; r < 48; ++r) {
        const unsigned* trow = &tile[(ty + r) * 14];
        unsigned w[14];
        #pragma unroll
        for (int i = 0; i < 14; ++i) w[i] = trow[i];
        unsigned wsel[13];
        #pragma unroll
        for (int i = 0; i < 13; ++i) wsel[i] = (tx & 4) ? w[i+1] : w[i];
        unsigned a[12];   // a[i] bytes = image bins at cols tx+4i .. tx+4i+3
        #pragma unroll
        for (int i = 0; i < 12; ++i)
            a[i] = (unsigned)(((((unsigned long long)wsel[i+1]) << 32) | (unsigned long long)wsel[i]) >> sh);

        const int tb = r * 6;
        unsigned tq0 = (unsigned)__builtin_amdgcn_readfirstlane((int)twl[tb+0]);
        unsigned tq1 = (unsigned)__builtin_amdgcn_readfirstlane((int)twl[tb+1]);
        unsigned tq2 = (unsigned)__builtin_amdgcn_readfirstlane((int)twl[tb+2]);
        unsigned tq3 = (unsigned)__builtin_amdgcn_readfirstlane((int)twl[tb+3]);
        unsigned tq4 = (unsigned)__builtin_amdgcn_readfirstlane((int)twl[tb+4]);
        unsigned tq5 = (unsigned)__builtin_amdgcn_readfirstlane((int)twl[tb+5]);
        unsigned tq[6] = {tq0, tq1, tq2, tq3, tq4, tq5};

        #pragma unroll
        for (int c = 0; c < 48; ++c) {
            unsigned bin = (a[c >> 2] >> ((c & 3) * 8)) & 0xFFu;     // 0..16
            unsigned l   = (tq[c >> 3] >> ((c & 7) * 4)) & 0xFu;     // wave-uniform
            unsigned addend = 1u << ((l & 1u) << 4);                 // low/high u16 half
            atomicAdd(&hist[histBase + bin * 8u + (l >> 1)], addend); // ds_add_u32
        }
    }

    // epilogue: MI from own histogram (rows 0..15; row 16 = OOB sentinel, ignored)
    float A = 0.0f;
    int coll[16];
    #pragma unroll
    for (int i = 0; i < 16; ++i) coll[i] = 0;
    int N = 0;
    #pragma unroll
    for (int k = 0; k < 16; ++k) {
        int rk = 0;
        #pragma unroll
        for (int wv = 0; wv < 8; ++wv) {
            unsigned v = hist[histBase + k*8 + wv];
            int c0 = (int)(v & 0xFFFFu), c1 = (int)(v >> 16);
            rk += c0 + c1;
            coll[2*wv]   += c0;
            coll[2*wv+1] += c1;
            if (c0) A += (float)c0 * logf((float)c0);
            if (c1) A += (float)c1 * logf((float)c1);
        }
        if (rk) A -= (float)rk * logf((float)rk);
        N += rk;
    }
    #pragma unroll
    for (int i = 0; i < 16; ++i)
        if (coll[i]) A -= (float)coll[i] * logf((float)coll[i]);
    float fN = (float)N;
    float mi = (A + fN * logf(fN)) / fN;
    out[(b * IMH + Y0 + ty) * IMW + X0 + tx] = mi;
}

extern "C" void kernel_launch(void* const* d_in, const int* in_sizes, int n_in,
                              void* d_out, int out_size, void* d_ws, size_t ws_size,
                              hipStream_t stream) {
    const float* im = (const float*)d_in[0];
    const float* tm = (const float*)d_in[1];
    float* out = (float*)d_out;
    unsigned char* pIm = (unsigned char*)d_ws;                      // 373248 B
    unsigned* pT  = (unsigned*)((char*)d_ws + 373248);              // 2304 B
    float* mnmx   = (float*)((char*)d_ws + 375552);                 // 32 B

    k_minmax<<<4, 256, 0, stream>>>(im, tm, mnmx);
    k_binpad<<<1458, 256, 0, stream>>>(im, mnmx, pIm);
    k_tpack<<<2, 64, 0, stream>>>(tm, mnmx, pT);
    k_main<<<dim3(48, 48, 2), 64, 0, stream>>>(pIm, pT, out);
}